// Round 5
// baseline (15093.280 us; speedup 1.0000x reference)
//
#include <hip/hip_runtime.h>
#include <cstdint>
#include <cstddef>

#define T_STEPS 1024
#define B_SZ    128
#define F_SZ    88
#define H_SZ    1024
#define C_SZ    88

// 128 gate WGs: 64 unit-groups (16 units) x 2 batch-halves (64 batches).
// BLOCK=256: 4 waves = 2 batch tiles x 2 k-halves (wave pair splits k=1024).
// 6 FC WGs: 3 col-groups x 2 batch-halves (waves 0,1 = tiles; 2,3 idle).
#define N_GATE_WG 128
#define N_FC_WG   6
#define N_COMPUTE (N_GATE_WG + N_FC_WG)         // 134
#define N_WG      N_COMPUTE
#define BLOCK     256
#define FLAG_STRIDE 16                          // ints -> 64 B per flag line
#define RING      16                            // h ring slots == inv period

typedef __attribute__((ext_vector_type(8)))  __bf16 bf16x8;
typedef __attribute__((ext_vector_type(16))) float  f32x16;
typedef __attribute__((ext_vector_type(4)))  int    i32x4;

// ---------------- LDS layout (bytes) ----------------
#define SLAB_OFF    0
#define SLAB_BYTES  (64 * 1024 * 2)             // 131072: W_hh (64 cols x 1024 k)
#define BIAS_OFF    (SLAB_OFF + SLAB_BYTES)     // 131072 (64 floats)
#define LENL_OFF    (BIAS_OFF + 256)            // 131328 (128 ints)
#define NB_OFF      (LENL_OFF + 512)            // 131840 (1025 ushort, padded)
#define EXCH_OFF    (NB_OFF + 2064)             // 133904 (16-aligned)
#define EXCH_TILE   (32 * 68 * 4)               // 8704 B per batch tile (stride-68 pad)
#define STAGE_OFF   (EXCH_OFF + 2 * EXCH_TILE)  // 151312 (16-aligned)
#define SMEM_BYTES  (STAGE_OFF + 2 * 512 * 2)   // 153360 (< 160 KiB)

// one h slot: 64 ktiles * 4 btiles * 64 lanes * 8 bf16  (layout identical to R4)
#define HBUF_ELEMS  131072
#define HBUF_BYTES  (HBUF_ELEMS * 2)            // 256 KB per slot, RING slots

__device__ __forceinline__ float sigm(float x) {
    return __builtin_amdgcn_rcpf(1.0f + __expf(-x));
}
__device__ __forceinline__ float tanh_fast(float x) {
    return 1.0f - 2.0f * __builtin_amdgcn_rcpf(__expf(2.0f * x) + 1.0f);
}
// write-through (agent-coherent) 8-byte store: lands at the LLC, bypassing
// the writer's L2 -> consumers' post-invalidate refills see fresh data.
__device__ __forceinline__ void st_llc(void* p, uint64_t v) {
    __hip_atomic_store((uint64_t*)p, v, __ATOMIC_RELAXED,
                       __HIP_MEMORY_SCOPE_AGENT);
}

extern "C" __global__ void __launch_bounds__(BLOCK, 1)
lstm_fused(const float* __restrict__ X,
           const int*   __restrict__ len_raw,
           const float* __restrict__ W_ih,
           const float* __restrict__ W_hh,
           const float* __restrict__ b_ih,
           const float* __restrict__ b_hh,
           const float* __restrict__ W_fc,
           const float* __restrict__ b_fc,
           float*       __restrict__ out,
           __bf16*      __restrict__ hbuf,
           int*         __restrict__ flags)
{
    extern __shared__ char smem[];
    __bf16*         slab  = (__bf16*)(smem + SLAB_OFF);
    float*          biasL = (float*)(smem + BIAS_OFF);
    int*            lenL  = (int*)(smem + LENL_OFF);
    unsigned short* nbL   = (unsigned short*)(smem + NB_OFF);

    const int  wg   = blockIdx.x;
    const int  tid  = threadIdx.x;
    const int  w    = tid >> 6;
    const int  lane = tid & 63;
    const int  col  = lane & 31;
    const int  h5   = lane >> 5;
    const bool isGate = (wg < N_GATE_WG);

    const int  tile = w >> 1;        // gate: batch tile within this WG's half
    const int  kh   = w & 1;         // gate: k-half (ktiles kh*32 .. kh*32+31)

    // decompose. Gate: wg = 8m + x; XCD x hosts only bt2 = x>>2, so co-XCD WGs
    // read the same 128 KB h sub-panel (L2-shared). ug = 4m + (x&3) in [0,64).
    int ug = 0, bt2 = 0, cg = 0;
    if (isGate) { int m = wg >> 3, x = wg & 7; bt2 = x >> 2; ug = 4 * m + (x & 3); }
    else        { int f = wg - N_GATE_WG; bt2 = f / 3; cg = f % 3; }
    const int bti  = bt2 * 2 + (isGate ? tile : w);   // FC only valid for w<2
    // per-half flag lines: [half*68 + ug] for gates, [half*68 + 64 + cg] for FC
    const int fidx  = bt2 * 68 + (isGate ? ug : (64 + cg));
    const int hbase = bt2 * 68;

    // ---------------- prologue ----------------
    const int lstride = (len_raw[1] == 0) ? 2 : 1;   // int64 vs int32 lengths
    if (tid < B_SZ) lenL[tid] = len_raw[tid * lstride];
    __syncthreads();
    for (int t = tid; t <= T_STEPS; t += BLOCK) {
        int cnt = 0;
        #pragma unroll 4
        for (int b = 0; b < B_SZ; ++b) cnt += (lenL[b] > t) ? 1 : 0;
        nbL[t] = (unsigned short)cnt;
    }
    // zero the partial-sum exchange regions (atomicAdd targets)
    for (int idx = tid; idx < 2 * (EXCH_TILE / 4); idx += BLOCK)
        ((float*)(smem + EXCH_OFF))[idx] = 0.0f;

    // W_ih B-fragments in registers: this wave's k-half only (2 n x 3 kt)
    bf16x8 wih[2][3];
    if (isGate) {
        // W_hh slab: 2 col-tiles n; within a tile permuted col cc = 4*ul + gate
        for (int idx = tid; idx < 64 * 1024; idx += BLOCK) {
            int cc2 = idx >> 10, k = idx & 1023;
            int n = cc2 >> 5, cc = cc2 & 31;
            int gate = cc & 3, ul = cc >> 2;
            int j = ug * 16 + n * 8 + ul;
            float v = W_hh[(size_t)(gate * H_SZ + j) * H_SZ + k];
            slab[(size_t)((k >> 4) * 128 + n * 64 + ((k >> 3) & 1) * 32 + cc) * 8 + (k & 7)] = (__bf16)v;
        }
        {
            const int gate = col & 3, ul = col >> 2;
            #pragma unroll
            for (int n = 0; n < 2; ++n) {
                const float* wrow = W_ih + (size_t)(gate * H_SZ + ug * 16 + n * 8 + ul) * F_SZ;
                #pragma unroll
                for (int j = 0; j < 3; ++j) {
                    const int f0 = (kh * 3 + j) * 16 + h5 * 8;
                    bf16x8 b;
                    #pragma unroll
                    for (int e = 0; e < 8; ++e) {
                        int k = f0 + e;
                        b[e] = (k < F_SZ) ? (__bf16)wrow[k] : (__bf16)0.0f;
                    }
                    wih[n][j] = b;
                }
            }
        }
        if (tid < 64) {
            int n = tid >> 5, cc = tid & 31, gate = cc & 3, ul = cc >> 2;
            int row = gate * H_SZ + ug * 16 + n * 8 + ul;
            biasL[tid] = b_ih[row] + b_hh[row];
        }
    } else {
        for (int idx = tid; idx < 32 * 1024; idx += BLOCK) {
            int cc = idx >> 10, k = idx & 1023;
            int c = cg * 32 + cc;
            float v = (c < C_SZ) ? W_fc[(size_t)c * H_SZ + k] : 0.0f;
            slab[(size_t)((k >> 4) * 64 + ((k >> 3) & 1) * 32 + cc) * 8 + (k & 7)] = (__bf16)v;
        }
        if (tid < 32) {
            int c = cg * 32 + tid;
            biasL[tid] = (c < C_SZ) ? b_fc[c] : 0.0f;
        }
    }

    __syncthreads();
    if (tid == 0) {
        __builtin_amdgcn_s_waitcnt(0);
        __hip_atomic_store(flags + fidx * FLAG_STRIDE, 1, __ATOMIC_RELAXED,
                           __HIP_MEMORY_SCOPE_AGENT);
    }

    const int a4    = col & 3;           // gate index of this lane (i,f,g,o)
    const int u0    = col >> 2;          // unit-local 0..7 within a col-tile
    const int c0fc  = cg * 32;
    const int phase = wg & (RING - 1);   // staggered-inv phase

    float*  exchT  = (float*)(smem + EXCH_OFF) + tile * (EXCH_TILE / 4);
    __bf16* stageW = (__bf16*)(smem + STAGE_OFF) + tile * 512;

    const bool hasFC = (lane < 3);       // lanes 0..2 also poll the half's FC lines
    long guard = 0;

    float c_reg[8] = {0.f,0.f,0.f,0.f,0.f,0.f,0.f,0.f};   // [n*4+q] (kh==0 only)
    float h_reg[8] = {0.f,0.f,0.f,0.f,0.f,0.f,0.f,0.f};

    for (int t = 0; t <= T_STEPS; ++t) {
        const int nb_t   = (t < T_STEPS) ? (int)nbL[t] : 0;
        const int nb_pre = (t > 0) ? (int)nbL[t - 1] : B_SZ;
        const __bf16* hin  = hbuf + (size_t)((t + RING - 1) & (RING - 1)) * HBUF_ELEMS;
        __bf16*       hout = hbuf + (size_t)(t & (RING - 1)) * HBUF_ELEMS;

        const bool gcomp = isGate && (t < T_STEPS) && (bti * 32 < nb_t);
        const bool gwrt  = isGate && (t < T_STEPS) && (bti * 32 < nb_pre);

        f32x16 acc[2];

        // ---- pre-barrier: bias/0 + x_t @ W_ih^T (this wave's 3 ksteps) ----
        if (gcomp) {
            #pragma unroll
            for (int n = 0; n < 2; ++n) {
                float bv = (kh == 0) ? biasL[n * 32 + col] : 0.0f;
                #pragma unroll
                for (int i = 0; i < 16; ++i) acc[n][i] = bv;
            }
            const float* xrow = X + ((size_t)t * B_SZ + (bti * 32 + col)) * F_SZ;
            #pragma unroll
            for (int j = 0; j < 3; ++j) {
                int f0 = (kh * 3 + j) * 16 + h5 * 8;
                bf16x8 a;
                if (f0 < F_SZ) {
                    float4 lo = *(const float4*)(xrow + f0);
                    float4 hi = *(const float4*)(xrow + f0 + 4);
                    a[0] = (__bf16)lo.x; a[1] = (__bf16)lo.y; a[2] = (__bf16)lo.z; a[3] = (__bf16)lo.w;
                    a[4] = (__bf16)hi.x; a[5] = (__bf16)hi.y; a[6] = (__bf16)hi.z; a[7] = (__bf16)hi.w;
                } else {
                    #pragma unroll
                    for (int e = 0; e < 8; ++e) a[e] = (__bf16)0.0f;
                }
                #pragma unroll
                for (int n = 0; n < 2; ++n)
                    acc[n] = __builtin_amdgcn_mfma_f32_32x32x16_bf16(a, wih[n][j], acc[n], 0, 0, 0);
            }
        }

        // ---- per-half barrier: wave 0 polls its half's 67 flag lines ----
        if (w == 0) {
            const int target = t + 1;
            for (;;) {
                int a = __hip_atomic_load(flags + (hbase + lane) * FLAG_STRIDE,
                                          __ATOMIC_RELAXED, __HIP_MEMORY_SCOPE_AGENT);
                int b = hasFC ? __hip_atomic_load(flags + (hbase + 64 + lane) * FLAG_STRIDE,
                                                  __ATOMIC_RELAXED, __HIP_MEMORY_SCOPE_AGENT)
                              : target;
                if (__all((a >= target) && (b >= target))) break;
                __builtin_amdgcn_s_sleep(1);
                if (++guard > 400000000L) break;     // anti-hang bail
            }
        }
        __syncthreads();   // [A] waves released; h loads can't hoist above

        // ---- staggered periodic acquire (buffer_inv), once per ring window ----
        if (((t + phase) & (RING - 1)) == 0) {
            if (tid == 0)
                __builtin_amdgcn_fence(__ATOMIC_ACQUIRE, "agent");
            __syncthreads();
        }

        // FC wgs arrive early (slack via the deep ring)
        if (!isGate && tid == 0) {
            __hip_atomic_store(flags + fidx * FLAG_STRIDE, t + 2, __ATOMIC_RELAXED,
                               __HIP_MEMORY_SCOPE_AGENT);
        }

        // ---- FC head: logits(t-1) from h(t-1) of this half's tiles ----
        if (!isGate && w < 2 && t >= 1) {
            const int  s        = t - 1;
            const int  nb_s     = (int)nbL[s];
            const bool act_tile = (bti * 32) < nb_s;
            f32x16 accf;
            #pragma unroll
            for (int i = 0; i < 16; ++i) accf[i] = 0.0f;
            if (act_tile) {
                float bv = biasL[col];
                #pragma unroll
                for (int i = 0; i < 16; ++i) accf[i] = bv;
                const __bf16* hA = hin + (size_t)bti * 512 + (size_t)lane * 8;
                const __bf16* bB = slab + lane * 8;
                #pragma unroll 8
                for (int kt = 0; kt < 64; ++kt) {
                    bf16x8 a = __builtin_bit_cast(bf16x8, *(const i32x4*)(hA + (size_t)kt * 2048));
                    bf16x8 b = __builtin_bit_cast(bf16x8, *(const i32x4*)(bB + (size_t)kt * 512));
                    accf = __builtin_amdgcn_mfma_f32_32x32x16_bf16(a, b, accf, 0, 0, 0);
                }
            }
            const int c = c0fc + col;
            if (c < C_SZ) {
                #pragma unroll
                for (int i = 0; i < 16; ++i) {
                    int row = (i & 3) + 8 * (i >> 2) + 4 * h5;
                    int b   = bti * 32 + row;
                    float v = (act_tile && b < nb_s) ? accf[i] : 0.0f;
                    float2 o2; o2.x = v; o2.y = 1.0f - v;
                    *(float2*)(out + ((size_t)(b * T_STEPS + s) * C_SZ + c) * 2) = o2;
                }
            }
        }

        // ---- gate phase 1: h(t-1)[k-half] @ W_hh^T, 32 loads all-outstanding ----
        if (gcomp && t > 0) {
            const __bf16* hA = hin + (size_t)(kh * 32) * 2048
                                   + (size_t)bti * 512 + (size_t)lane * 8;
            const __bf16* bB = slab + lane * 8;
            i32x4 pf[32];
            #pragma unroll
            for (int i = 0; i < 32; ++i)
                pf[i] = *(const i32x4*)(hA + (size_t)i * 2048);
            __builtin_amdgcn_sched_barrier(0);   // keep all 32 loads clustered first
            #pragma unroll
            for (int i = 0; i < 32; ++i) {
                bf16x8 a = __builtin_bit_cast(bf16x8, pf[i]);
                const int ks = kh * 32 + i;
                bf16x8 b0 = __builtin_bit_cast(bf16x8,
                    *(const i32x4*)(bB + (size_t)ks * 1024));
                acc[0] = __builtin_amdgcn_mfma_f32_32x32x16_bf16(a, b0, acc[0], 0, 0, 0);
                bf16x8 b1 = __builtin_bit_cast(bf16x8,
                    *(const i32x4*)(bB + (size_t)ks * 1024 + 512));
                acc[1] = __builtin_amdgcn_mfma_f32_32x32x16_bf16(a, b1, acc[1], 0, 0, 0);
            }
            __builtin_amdgcn_sched_barrier(0);
        }
        // combine k-half partials into the shared per-tile region
        if (gcomp) {
            #pragma unroll
            for (int n = 0; n < 2; ++n)
                #pragma unroll
                for (int j = 0; j < 16; ++j)
                    atomicAdd(&exchT[(n * 16 + j) * 68 + lane], acc[n][j]);
        }
        __syncthreads();   // [B] both k-halves' adds complete

        // ---- gate phase 2 (kh==0): activations + state update; reset exch ----
        if (gcomp && kh == 0) {
            #pragma unroll
            for (int n = 0; n < 2; ++n) {
                #pragma unroll
                for (int q = 0; q < 4; ++q) {
                    float4* vp = (float4*)(exchT + (n * 16 + 4 * a4 + q) * 68 + 32 * h5 + (col & ~3));
                    const float4 v = *vp;
                    float4 z; z.x = 0.f; z.y = 0.f; z.z = 0.f; z.w = 0.f;
                    *vp = z;                          // re-zero for next step's adds
                    float si = sigm(v.x);
                    float sf = sigm(v.y);
                    float tg = tanh_fast(v.z);
                    float so = sigm(v.w);
                    float cn = sf * c_reg[n * 4 + q] + si * tg;
                    float hn = so * tanh_fast(cn);
                    int b = bti * 32 + 8 * a4 + 4 * h5 + q;
                    if (b < nb_t) { c_reg[n * 4 + q] = cn; h_reg[n * 4 + q] = hn; }
                }
            }
        }
        if (gwrt && kh == 0) {
            #pragma unroll
            for (int n = 0; n < 2; ++n)
                #pragma unroll
                for (int q = 0; q < 4; ++q)
                    stageW[(8 * a4 + 4 * h5 + q) * 16 + n * 8 + u0] = (__bf16)h_reg[n * 4 + q];
        }
        __syncthreads();   // [D]

        // ---- gate phase 3 (kh==0): write-through store of h(t) ktile to LLC ----
        if (gwrt && kh == 0) {
            const uint64_t* sp = (const uint64_t*)(stageW + (size_t)col * 16 + (size_t)h5 * 8);
            uint64_t* hp = (uint64_t*)(hout + (size_t)ug * 2048 + (size_t)bti * 512 + (size_t)lane * 8);
            st_llc(hp,     sp[0]);
            st_llc(hp + 1, sp[1]);
        }
        __syncthreads();   // [E] per-wave vmcnt(0) drain: h(t) at the LLC after this

        if (isGate && tid == 0) {
            __builtin_amdgcn_s_waitcnt(0);
            __hip_atomic_store(flags + fidx * FLAG_STRIDE, t + 2, __ATOMIC_RELAXED,
                               __HIP_MEMORY_SCOPE_AGENT);
        }
    }
}

extern "C" void kernel_launch(void* const* d_in, const int* in_sizes, int n_in,
                              void* d_out, int out_size, void* d_ws, size_t ws_size,
                              hipStream_t stream) {
    const float* X    = (const float*)d_in[0];
    const int*   lens = (const int*)d_in[1];
    const float* Wih  = (const float*)d_in[2];
    const float* Whh  = (const float*)d_in[3];
    const float* bih  = (const float*)d_in[4];
    const float* bhh  = (const float*)d_in[5];
    const float* Wfc  = (const float*)d_in[6];
    const float* bfc  = (const float*)d_in[7];
    float*       outp = (float*)d_out;

    __bf16* hbuf  = (__bf16*)d_ws;                                 // RING x 256 KB
    int*    flags = (int*)((char*)d_ws + (size_t)RING * HBUF_BYTES);

    (void)hipFuncSetAttribute((const void*)lstm_fused,
                              hipFuncAttributeMaxDynamicSharedMemorySize, SMEM_BYTES);

    void* args[] = { (void*)&X, (void*)&lens, (void*)&Wih, (void*)&Whh,
                     (void*)&bih, (void*)&bhh, (void*)&Wfc, (void*)&bfc,
                     (void*)&outp, (void*)&hbuf, (void*)&flags };
    hipError_t le = hipLaunchCooperativeKernel((void*)lstm_fused, dim3(N_WG), dim3(BLOCK),
                                               args, (unsigned)SMEM_BYTES, stream);
    if (le != hipSuccess) {
        // fallback: plain launch. 134 WGs, 1 per CU (LDS-limited) on 256 CUs are
        // co-resident; the kernel uses only its own flag barrier, no cg grid sync.
        hipLaunchKernelGGL(lstm_fused, dim3(N_WG), dim3(BLOCK),
                           (unsigned)SMEM_BYTES, stream,
                           X, lens, Wih, Whh, bih, bhh, Wfc, bfc, outp, hbuf, flags);
    }
}

// Round 6
// 7561.642 us; speedup vs baseline: 1.9960x; 1.9960x over previous
//
#include <hip/hip_runtime.h>
#include <cstdint>
#include <cstddef>

#define T_STEPS 1024
#define B_SZ    128
#define F_SZ    88
#define H_SZ    1024
#define C_SZ    88

// 128 gate WGs: 64 unit-groups (16 units) x 2 batch-halves (64 batches).
// 6 FC WGs: 3 col-groups x 2 batch-halves. BLOCK=128: wave = one 32-batch tile.
// The two batch-halves are fully independent recurrences -> two disjoint
// 67-WG barrier groups (gates 64 + FC 3 each).
#define N_GATE_WG 128
#define N_FC_WG   6
#define N_COMPUTE (N_GATE_WG + N_FC_WG)         // 134
#define N_WG      N_COMPUTE
#define BLOCK     128
#define FLAG_STRIDE 16                          // ints -> 64 B per flag line
#define RING      16                            // h ring slots == inv period

typedef __attribute__((ext_vector_type(8)))  __bf16 bf16x8;
typedef __attribute__((ext_vector_type(16))) float  f32x16;
typedef __attribute__((ext_vector_type(4)))  int    i32x4;

// ---------------- LDS layout (bytes) ----------------
#define SLAB_OFF    0
#define SLAB_BYTES  (64 * 1024 * 2)             // 131072: W_hh (64 cols x 1024 k)
#define BIAS_OFF    (SLAB_OFF + SLAB_BYTES)     // 131072 (64 floats)
#define LENL_OFF    (BIAS_OFF + 256)            // 131328 (128 ints)
#define NB_OFF      (LENL_OFF + 512)            // 131840 (1025 ushort, padded)
#define EXCH_OFF    (NB_OFF + 2064)             // 133904 (16-aligned)
#define EXCH_WAVE   (32 * 68 * 4)               // 8704 B per wave (32 rows, stride-68 pad)
#define STAGE_OFF   (EXCH_OFF + 2 * EXCH_WAVE)  // 151312 (16-aligned)
#define SMEM_BYTES  (STAGE_OFF + 2 * 512 * 2)   // 153360 (< 160 KiB)

// one h slot: 64 ktiles * 4 btiles * 64 lanes * 8 bf16  (layout identical to R4)
#define HBUF_ELEMS  131072
#define HBUF_BYTES  (HBUF_ELEMS * 2)            // 256 KB per slot, RING slots

__device__ __forceinline__ float sigm(float x) {
    return __builtin_amdgcn_rcpf(1.0f + __expf(-x));
}
__device__ __forceinline__ float tanh_fast(float x) {
    return 1.0f - 2.0f * __builtin_amdgcn_rcpf(__expf(2.0f * x) + 1.0f);
}
// write-through (agent-coherent) 8-byte store: lands at the LLC, bypassing
// the writer's L2 -> consumers' post-invalidate refills see fresh data.
__device__ __forceinline__ void st_llc(void* p, uint64_t v) {
    __hip_atomic_store((uint64_t*)p, v, __ATOMIC_RELAXED,
                       __HIP_MEMORY_SCOPE_AGENT);
}

extern "C" __global__ void __launch_bounds__(BLOCK, 1)
lstm_fused(const float* __restrict__ X,
           const int*   __restrict__ len_raw,
           const float* __restrict__ W_ih,
           const float* __restrict__ W_hh,
           const float* __restrict__ b_ih,
           const float* __restrict__ b_hh,
           const float* __restrict__ W_fc,
           const float* __restrict__ b_fc,
           float*       __restrict__ out,
           __bf16*      __restrict__ hbuf,
           int*         __restrict__ flags)
{
    extern __shared__ char smem[];
    __bf16*         slab  = (__bf16*)(smem + SLAB_OFF);
    float*          biasL = (float*)(smem + BIAS_OFF);
    int*            lenL  = (int*)(smem + LENL_OFF);
    unsigned short* nbL   = (unsigned short*)(smem + NB_OFF);

    const int  wg   = blockIdx.x;
    const int  tid  = threadIdx.x;
    const int  w    = tid >> 6;      // wave = batch tile within this WG's half
    const int  lane = tid & 63;
    const int  col  = lane & 31;
    const int  h5   = lane >> 5;
    const bool isGate = (wg < N_GATE_WG);

    // decompose. Gate: wg = 8m + x; XCD x hosts only bt2 = x>>2, so co-XCD WGs
    // read the same 128 KB h sub-panel (L2-shared). ug = 4m + (x&3) in [0,64).
    int ug = 0, bt2 = 0, cg = 0;
    if (isGate) { int m = wg >> 3, x = wg & 7; bt2 = x >> 2; ug = 4 * m + (x & 3); }
    else        { int f = wg - N_GATE_WG; bt2 = f / 3; cg = f % 3; }
    const int bti  = bt2 * 2 + w;        // this wave's batch tile 0..3
    // per-half flag lines: [half*68 + ug] for gates, [half*68 + 64 + cg] for FC
    const int fidx = bt2 * 68 + (isGate ? ug : (64 + cg));
    const int hbase = bt2 * 68;

    // ---------------- prologue ----------------
    const int lstride = (len_raw[1] == 0) ? 2 : 1;   // int64 vs int32 lengths
    if (tid < B_SZ) lenL[tid] = len_raw[tid * lstride];
    __syncthreads();
    for (int t = tid; t <= T_STEPS; t += BLOCK) {
        int cnt = 0;
        #pragma unroll 4
        for (int b = 0; b < B_SZ; ++b) cnt += (lenL[b] > t) ? 1 : 0;
        nbL[t] = (unsigned short)cnt;
    }

    // W_ih B-fragments in registers (2 col-tiles x 6 ksteps = 48 VGPRs/lane)
    bf16x8 wih[2][6];
    if (isGate) {
        // W_hh slab: 2 col-tiles n; within a tile permuted col cc = 4*ul + gate
        for (int idx = tid; idx < 64 * 1024; idx += BLOCK) {
            int cc2 = idx >> 10, k = idx & 1023;
            int n = cc2 >> 5, cc = cc2 & 31;
            int gate = cc & 3, ul = cc >> 2;
            int j = ug * 16 + n * 8 + ul;
            float v = W_hh[(size_t)(gate * H_SZ + j) * H_SZ + k];
            slab[(size_t)((k >> 4) * 128 + n * 64 + ((k >> 3) & 1) * 32 + cc) * 8 + (k & 7)] = (__bf16)v;
        }
        {
            const int gate = col & 3, ul = col >> 2;
            #pragma unroll
            for (int n = 0; n < 2; ++n) {
                const float* wrow = W_ih + (size_t)(gate * H_SZ + ug * 16 + n * 8 + ul) * F_SZ;
                #pragma unroll
                for (int kt = 0; kt < 6; ++kt) {
                    const int f0 = kt * 16 + h5 * 8;
                    bf16x8 b;
                    #pragma unroll
                    for (int e = 0; e < 8; ++e) {
                        int k = f0 + e;
                        b[e] = (k < F_SZ) ? (__bf16)wrow[k] : (__bf16)0.0f;
                    }
                    wih[n][kt] = b;
                }
            }
        }
        if (tid < 64) {
            int n = tid >> 5, cc = tid & 31, gate = cc & 3, ul = cc >> 2;
            int row = gate * H_SZ + ug * 16 + n * 8 + ul;
            biasL[tid] = b_ih[row] + b_hh[row];
        }
    } else {
        for (int idx = tid; idx < 32 * 1024; idx += BLOCK) {
            int cc = idx >> 10, k = idx & 1023;
            int c = cg * 32 + cc;
            float v = (c < C_SZ) ? W_fc[(size_t)c * H_SZ + k] : 0.0f;
            slab[(size_t)((k >> 4) * 64 + ((k >> 3) & 1) * 32 + cc) * 8 + (k & 7)] = (__bf16)v;
        }
        if (tid < 32) {
            int c = cg * 32 + tid;
            biasL[tid] = (c < C_SZ) ? b_fc[c] : 0.0f;
        }
    }

    __syncthreads();
    if (tid == 0) {
        __builtin_amdgcn_s_waitcnt(0);
        __hip_atomic_store(flags + fidx * FLAG_STRIDE, 1, __ATOMIC_RELAXED,
                           __HIP_MEMORY_SCOPE_AGENT);
    }

    const int a4    = col & 3;           // gate index of this lane (i,f,g,o)
    const int u0    = col >> 2;          // unit-local 0..7 within a col-tile
    const int c0fc  = cg * 32;
    const int phase = wg & (RING - 1);   // staggered-inv phase

    float*  exch   = (float*)(smem + EXCH_OFF) + w * (EXCH_WAVE / 4);
    __bf16* stageW = (__bf16*)(smem + STAGE_OFF) + w * 512;

    const bool hasFC = (lane < 3);       // lanes 0..2 also poll the half's FC lines
    long guard = 0;

    float c_reg[8] = {0.f,0.f,0.f,0.f,0.f,0.f,0.f,0.f};   // [n*4+q]
    float h_reg[8] = {0.f,0.f,0.f,0.f,0.f,0.f,0.f,0.f};

    for (int t = 0; t <= T_STEPS; ++t) {
        const int nb_t   = (t < T_STEPS) ? (int)nbL[t] : 0;
        const int nb_pre = (t > 0) ? (int)nbL[t - 1] : B_SZ;
        const __bf16* hin  = hbuf + (size_t)((t + RING - 1) & (RING - 1)) * HBUF_ELEMS;
        __bf16*       hout = hbuf + (size_t)(t & (RING - 1)) * HBUF_ELEMS;

        const bool gcomp = isGate && (t < T_STEPS) && (bti * 32 < nb_t);
        const bool gwrt  = isGate && (t < T_STEPS) && (bti * 32 < nb_pre);

        f32x16 acc[2];

        // ---- pre-barrier: bias + x_t @ W_ih^T (independent of h(t-1)) ----
        if (gcomp) {
            #pragma unroll
            for (int n = 0; n < 2; ++n) {
                float bv = biasL[n * 32 + col];
                #pragma unroll
                for (int i = 0; i < 16; ++i) acc[n][i] = bv;
            }
            const float* xrow = X + ((size_t)t * B_SZ + (bti * 32 + col)) * F_SZ;
            #pragma unroll
            for (int kt = 0; kt < 6; ++kt) {
                int f0 = kt * 16 + h5 * 8;
                bf16x8 a;
                if (f0 < F_SZ) {
                    float4 lo = *(const float4*)(xrow + f0);
                    float4 hi = *(const float4*)(xrow + f0 + 4);
                    a[0] = (__bf16)lo.x; a[1] = (__bf16)lo.y; a[2] = (__bf16)lo.z; a[3] = (__bf16)lo.w;
                    a[4] = (__bf16)hi.x; a[5] = (__bf16)hi.y; a[6] = (__bf16)hi.z; a[7] = (__bf16)hi.w;
                } else {
                    #pragma unroll
                    for (int j = 0; j < 8; ++j) a[j] = (__bf16)0.0f;
                }
                #pragma unroll
                for (int n = 0; n < 2; ++n)
                    acc[n] = __builtin_amdgcn_mfma_f32_32x32x16_bf16(a, wih[n][kt], acc[n], 0, 0, 0);
            }
        }

        // ---- per-half barrier: wave 0 polls its half's 67 flag lines ----
        if (w == 0) {
            const int target = t + 1;
            for (;;) {
                int a = __hip_atomic_load(flags + (hbase + lane) * FLAG_STRIDE,
                                          __ATOMIC_RELAXED, __HIP_MEMORY_SCOPE_AGENT);
                int b = hasFC ? __hip_atomic_load(flags + (hbase + 64 + lane) * FLAG_STRIDE,
                                                  __ATOMIC_RELAXED, __HIP_MEMORY_SCOPE_AGENT)
                              : target;
                if (__all((a >= target) && (b >= target))) break;
                __builtin_amdgcn_s_sleep(1);
                if (++guard > 400000000L) break;     // anti-hang bail
            }
        }
        __syncthreads();   // [A] wave 1 released here; h loads can't hoist above

        // ---- staggered periodic acquire (buffer_inv), once per ring window ----
        if (((t + phase) & (RING - 1)) == 0) {
            if (tid == 0)
                __builtin_amdgcn_fence(__ATOMIC_ACQUIRE, "agent");
            __syncthreads();
        }

        // FC wgs arrive early (slack via the deep ring)
        if (!isGate && tid == 0) {
            __hip_atomic_store(flags + fidx * FLAG_STRIDE, t + 2, __ATOMIC_RELAXED,
                               __HIP_MEMORY_SCOPE_AGENT);
        }

        // ---- FC head: logits(t-1) from h(t-1) of this half's tiles ----
        if (!isGate && t >= 1) {
            const int  s        = t - 1;
            const int  nb_s     = (int)nbL[s];
            const bool act_tile = (bti * 32) < nb_s;
            f32x16 accf;
            #pragma unroll
            for (int i = 0; i < 16; ++i) accf[i] = 0.0f;
            if (act_tile) {
                float bv = biasL[col];
                #pragma unroll
                for (int i = 0; i < 16; ++i) accf[i] = bv;
                const __bf16* hA = hin + (size_t)bti * 512 + (size_t)lane * 8;
                const __bf16* bB = slab + lane * 8;
                #pragma unroll 8
                for (int kt = 0; kt < 64; ++kt) {
                    bf16x8 a = __builtin_bit_cast(bf16x8, *(const i32x4*)(hA + (size_t)kt * 2048));
                    bf16x8 b = __builtin_bit_cast(bf16x8, *(const i32x4*)(bB + (size_t)kt * 512));
                    accf = __builtin_amdgcn_mfma_f32_32x32x16_bf16(a, b, accf, 0, 0, 0);
                }
            }
            const int c = c0fc + col;
            if (c < C_SZ) {
                #pragma unroll
                for (int i = 0; i < 16; ++i) {
                    int row = (i & 3) + 8 * (i >> 2) + 4 * h5;
                    int b   = bti * 32 + row;
                    float v = (act_tile && b < nb_s) ? accf[i] : 0.0f;
                    float2 o2; o2.x = v; o2.y = 1.0f - v;
                    *(float2*)(out + ((size_t)(b * T_STEPS + s) * C_SZ + c) * 2) = o2;
                }
            }
        }

        // ---- gate phase 1: h(t-1) @ W_hh^T, 2-ahead double-buffer pipeline ----
        // Issue chunks 0 and 1 up front (32 loads in flight); in iteration c,
        // re-issue element i of chunk c+2 into cur[i] right after its MFMA
        // consumes cur[i] (WAR-safe: VALU reads operands at issue). One initial
        // latency window instead of R4's four.
        if (gcomp && t > 0) {
            const __bf16* hA = hin + (size_t)bti * 512 + (size_t)lane * 8;
            const __bf16* bB = slab + lane * 8;
            i32x4 pf0[16], pf1[16];
            #pragma unroll
            for (int i = 0; i < 16; ++i)
                pf0[i] = *(const i32x4*)(hA + (size_t)i * 2048);
            #pragma unroll
            for (int i = 0; i < 16; ++i)
                pf1[i] = *(const i32x4*)(hA + (size_t)(16 + i) * 2048);
            __builtin_amdgcn_sched_barrier(0);   // keep the 32-load burst clustered
            #pragma unroll
            for (int c = 0; c < 4; ++c) {
                i32x4 (&cur)[16] = (c & 1) ? pf1 : pf0;
                #pragma unroll
                for (int i = 0; i < 16; ++i) {
                    bf16x8 a = __builtin_bit_cast(bf16x8, cur[i]);
                    const int ks = c * 16 + i;
                    bf16x8 b0 = __builtin_bit_cast(bf16x8,
                        *(const i32x4*)(bB + (size_t)ks * 1024));
                    acc[0] = __builtin_amdgcn_mfma_f32_32x32x16_bf16(a, b0, acc[0], 0, 0, 0);
                    bf16x8 b1 = __builtin_bit_cast(bf16x8,
                        *(const i32x4*)(bB + (size_t)ks * 1024 + 512));
                    acc[1] = __builtin_amdgcn_mfma_f32_32x32x16_bf16(a, b1, acc[1], 0, 0, 0);
                    if (c < 2)   // refill this slot with chunk c+2's element i
                        cur[i] = *(const i32x4*)(hA + (size_t)((c + 2) * 16 + i) * 2048);
                }
                __builtin_amdgcn_sched_barrier(0);
            }
        }
        if (gcomp) {
            #pragma unroll
            for (int n = 0; n < 2; ++n)
                #pragma unroll
                for (int j = 0; j < 16; ++j)
                    exch[(n * 16 + j) * 68 + lane] = acc[n][j];
        }
        __syncthreads();

        // ---- gate phase 2: activations + state update + h staging ----
        if (gcomp) {
            #pragma unroll
            for (int n = 0; n < 2; ++n) {
                #pragma unroll
                for (int q = 0; q < 4; ++q) {
                    const float4 v = *(const float4*)(exch + (n * 16 + 4 * a4 + q) * 68 + 32 * h5 + (col & ~3));
                    float si = sigm(v.x);
                    float sf = sigm(v.y);
                    float tg = tanh_fast(v.z);
                    float so = sigm(v.w);
                    float cn = sf * c_reg[n * 4 + q] + si * tg;
                    float hn = so * tanh_fast(cn);
                    int b = bti * 32 + 8 * a4 + 4 * h5 + q;
                    if (b < nb_t) { c_reg[n * 4 + q] = cn; h_reg[n * 4 + q] = hn; }
                }
            }
        }
        if (gwrt) {
            #pragma unroll
            for (int n = 0; n < 2; ++n)
                #pragma unroll
                for (int q = 0; q < 4; ++q)
                    stageW[(8 * a4 + 4 * h5 + q) * 16 + n * 8 + u0] = (__bf16)h_reg[n * 4 + q];
        }
        __syncthreads();

        // ---- gate phase 3: write-through store of h(t) ktile to LLC ----
        if (gwrt) {
            const uint64_t* sp = (const uint64_t*)(stageW + (size_t)col * 16 + (size_t)h5 * 8);
            uint64_t* hp = (uint64_t*)(hout + (size_t)ug * 2048 + (size_t)bti * 512 + (size_t)lane * 8);
            st_llc(hp,     sp[0]);
            st_llc(hp + 1, sp[1]);
        }
        __syncthreads();   // per-wave vmcnt(0) drain: h(t) is at the LLC after this

        if (isGate && tid == 0) {
            __builtin_amdgcn_s_waitcnt(0);
            __hip_atomic_store(flags + fidx * FLAG_STRIDE, t + 2, __ATOMIC_RELAXED,
                               __HIP_MEMORY_SCOPE_AGENT);
        }
    }
}

extern "C" void kernel_launch(void* const* d_in, const int* in_sizes, int n_in,
                              void* d_out, int out_size, void* d_ws, size_t ws_size,
                              hipStream_t stream) {
    const float* X    = (const float*)d_in[0];
    const int*   lens = (const int*)d_in[1];
    const float* Wih  = (const float*)d_in[2];
    const float* Whh  = (const float*)d_in[3];
    const float* bih  = (const float*)d_in[4];
    const float* bhh  = (const float*)d_in[5];
    const float* Wfc  = (const float*)d_in[6];
    const float* bfc  = (const float*)d_in[7];
    float*       outp = (float*)d_out;

    __bf16* hbuf  = (__bf16*)d_ws;                                 // RING x 256 KB
    int*    flags = (int*)((char*)d_ws + (size_t)RING * HBUF_BYTES);

    (void)hipFuncSetAttribute((const void*)lstm_fused,
                              hipFuncAttributeMaxDynamicSharedMemorySize, SMEM_BYTES);

    void* args[] = { (void*)&X, (void*)&lens, (void*)&Wih, (void*)&Whh,
                     (void*)&bih, (void*)&bhh, (void*)&Wfc, (void*)&bfc,
                     (void*)&outp, (void*)&hbuf, (void*)&flags };
    hipError_t le = hipLaunchCooperativeKernel((void*)lstm_fused, dim3(N_WG), dim3(BLOCK),
                                               args, (unsigned)SMEM_BYTES, stream);
    if (le != hipSuccess) {
        // fallback: plain launch. 134 WGs, 1 per CU (LDS-limited) on 256 CUs are
        // co-resident; the kernel uses only its own flag barrier, no cg grid sync.
        hipLaunchKernelGGL(lstm_fused, dim3(N_WG), dim3(BLOCK),
                           (unsigned)SMEM_BYTES, stream,
                           X, lens, Wih, Whh, bih, bhh, Wfc, bfc, outp, hbuf, flags);
    }
}

// Round 7
// 7502.028 us; speedup vs baseline: 2.0119x; 1.0079x over previous
//
#include <hip/hip_runtime.h>
#include <cstdint>
#include <cstddef>

#define T_STEPS 1024
#define B_SZ    128
#define F_SZ    88
#define H_SZ    1024
#define C_SZ    88

// 128 gate WGs: 64 unit-groups (16 units) x 2 batch-halves; BLOCK=128, each
// wave owns one 32-batch tile. 6 FC WGs: 3 col-groups x 2 halves, wave = tile.
// Waves are AUTONOMOUS: no __syncthreads in the step loop. Barrier groups are
// per (half,tile) = bti: a closed set of 64 gate waves + 3 FC waves.
#define N_GATE_WG 128
#define N_FC_WG   6
#define N_COMPUTE (N_GATE_WG + N_FC_WG)         // 134
#define N_WG      N_COMPUTE
#define BLOCK     128
#define FLAG_STRIDE 16                          // ints -> 64 B per flag line
#define RING      16                            // h ring slots == inv period

typedef __attribute__((ext_vector_type(8)))  __bf16 bf16x8;
typedef __attribute__((ext_vector_type(16))) float  f32x16;
typedef __attribute__((ext_vector_type(4)))  int    i32x4;

// ---------------- LDS layout (bytes) ----------------
#define SLAB_OFF    0
#define SLAB_BYTES  (64 * 1024 * 2)             // 131072: W_hh (64 cols x 1024 k)
#define BIAS_OFF    (SLAB_OFF + SLAB_BYTES)     // 131072 (64 floats)
#define LENL_OFF    (BIAS_OFF + 256)            // 131328 (128 ints)
#define NB_OFF      (LENL_OFF + 512)            // 131840 (1025 ushort, padded)
#define EXCH_OFF    (NB_OFF + 2064)             // 133904 (16-aligned)
#define EXCH_WAVE   (32 * 68 * 4)               // 8704 B per wave (32 rows, stride-68 pad)
#define STAGE_OFF   (EXCH_OFF + 2 * EXCH_WAVE)  // 151312 (16-aligned)
#define SMEM_BYTES  (STAGE_OFF + 2 * 512 * 2)   // 153360 (< 160 KiB)

// one h slot: 64 ktiles * 4 btiles * 64 lanes * 8 bf16  (layout identical to R4/R6)
#define HBUF_ELEMS  131072
#define HBUF_BYTES  (HBUF_ELEMS * 2)            // 256 KB per slot, RING slots

__device__ __forceinline__ float sigm(float x) {
    return __builtin_amdgcn_rcpf(1.0f + __expf(-x));
}
__device__ __forceinline__ float tanh_fast(float x) {
    return 1.0f - 2.0f * __builtin_amdgcn_rcpf(__expf(2.0f * x) + 1.0f);
}
// write-through (agent-coherent) 8-byte store: lands at the LLC, bypassing
// the writer's L2 -> consumers' post-invalidate refills see fresh data.
__device__ __forceinline__ void st_llc(void* p, uint64_t v) {
    __hip_atomic_store((uint64_t*)p, v, __ATOMIC_RELAXED,
                       __HIP_MEMORY_SCOPE_AGENT);
}

extern "C" __global__ void __launch_bounds__(BLOCK, 1)
lstm_fused(const float* __restrict__ X,
           const int*   __restrict__ len_raw,
           const float* __restrict__ W_ih,
           const float* __restrict__ W_hh,
           const float* __restrict__ b_ih,
           const float* __restrict__ b_hh,
           const float* __restrict__ W_fc,
           const float* __restrict__ b_fc,
           float*       __restrict__ out,
           __bf16*      __restrict__ hbuf,
           int*         __restrict__ flags)
{
    extern __shared__ char smem[];
    __bf16*         slab  = (__bf16*)(smem + SLAB_OFF);
    float*          biasL = (float*)(smem + BIAS_OFF);
    int*            lenL  = (int*)(smem + LENL_OFF);
    unsigned short* nbL   = (unsigned short*)(smem + NB_OFF);

    const int  wg   = blockIdx.x;
    const int  tid  = threadIdx.x;
    const int  w    = tid >> 6;      // wave = batch tile within this WG's half
    const int  lane = tid & 63;
    const int  col  = lane & 31;
    const int  h5   = lane >> 5;
    const bool isGate = (wg < N_GATE_WG);

    // decompose. Gate: wg = 8m + x; XCD x hosts only bt2 = x>>2, so co-XCD WGs
    // read the same 128 KB h sub-panel (L2-shared). ug = 4m + (x&3) in [0,64).
    int ug = 0, bt2 = 0, cg = 0;
    if (isGate) { int m = wg >> 3, x = wg & 7; bt2 = x >> 2; ug = 4 * m + (x & 3); }
    else        { int f = wg - N_GATE_WG; bt2 = f / 3; cg = f % 3; }
    const int bti  = bt2 * 2 + w;        // this wave's batch tile 0..3 == group id
    // per-group flag lines: [bti*68 + ug] gates, [bti*68 + 64 + cg] FC
    const int fidx  = bti * 68 + (isGate ? ug : (64 + cg));
    const int gbase = bti * 68;

    // ---------------- prologue ----------------
    const int lstride = (len_raw[1] == 0) ? 2 : 1;   // int64 vs int32 lengths
    if (tid < B_SZ) lenL[tid] = len_raw[tid * lstride];
    __syncthreads();
    for (int t = tid; t <= T_STEPS; t += BLOCK) {
        int cnt = 0;
        #pragma unroll 4
        for (int b = 0; b < B_SZ; ++b) cnt += (lenL[b] > t) ? 1 : 0;
        nbL[t] = (unsigned short)cnt;
    }

    // W_ih B-fragments in registers (2 col-tiles x 6 ksteps = 48 VGPRs/lane)
    bf16x8 wih[2][6];
    if (isGate) {
        // W_hh slab: 2 col-tiles n; within a tile permuted col cc = 4*ul + gate
        for (int idx = tid; idx < 64 * 1024; idx += BLOCK) {
            int cc2 = idx >> 10, k = idx & 1023;
            int n = cc2 >> 5, cc = cc2 & 31;
            int gate = cc & 3, ul = cc >> 2;
            int j = ug * 16 + n * 8 + ul;
            float v = W_hh[(size_t)(gate * H_SZ + j) * H_SZ + k];
            slab[(size_t)((k >> 4) * 128 + n * 64 + ((k >> 3) & 1) * 32 + cc) * 8 + (k & 7)] = (__bf16)v;
        }
        {
            const int gate = col & 3, ul = col >> 2;
            #pragma unroll
            for (int n = 0; n < 2; ++n) {
                const float* wrow = W_ih + (size_t)(gate * H_SZ + ug * 16 + n * 8 + ul) * F_SZ;
                #pragma unroll
                for (int kt = 0; kt < 6; ++kt) {
                    const int f0 = kt * 16 + h5 * 8;
                    bf16x8 b;
                    #pragma unroll
                    for (int e = 0; e < 8; ++e) {
                        int k = f0 + e;
                        b[e] = (k < F_SZ) ? (__bf16)wrow[k] : (__bf16)0.0f;
                    }
                    wih[n][kt] = b;
                }
            }
        }
        if (tid < 64) {
            int n = tid >> 5, cc = tid & 31, gate = cc & 3, ul = cc >> 2;
            int row = gate * H_SZ + ug * 16 + n * 8 + ul;
            biasL[tid] = b_ih[row] + b_hh[row];
        }
    } else {
        for (int idx = tid; idx < 32 * 1024; idx += BLOCK) {
            int cc = idx >> 10, k = idx & 1023;
            int c = cg * 32 + cc;
            float v = (c < C_SZ) ? W_fc[(size_t)c * H_SZ + k] : 0.0f;
            slab[(size_t)((k >> 4) * 64 + ((k >> 3) & 1) * 32 + cc) * 8 + (k & 7)] = (__bf16)v;
        }
        if (tid < 32) {
            int c = cg * 32 + tid;
            biasL[tid] = (c < C_SZ) ? b_fc[c] : 0.0f;
        }
    }

    __syncthreads();                     // last block-wide barrier: slab complete
    __builtin_amdgcn_s_waitcnt(0);
    if (lane == 0)
        __hip_atomic_store(flags + fidx * FLAG_STRIDE, 1, __ATOMIC_RELAXED,
                           __HIP_MEMORY_SCOPE_AGENT);

    const int a4    = col & 3;           // gate index of this lane (i,f,g,o)
    const int u0    = col >> 2;          // unit-local 0..7 within a col-tile
    const int c0fc  = cg * 32;
    const int phase = wg & (RING - 1);   // staggered-inv phase

    float*  exch   = (float*)(smem + EXCH_OFF) + w * (EXCH_WAVE / 4);
    __bf16* stageW = (__bf16*)(smem + STAGE_OFF) + w * 512;

    long guard = 0;

    float c_reg[8] = {0.f,0.f,0.f,0.f,0.f,0.f,0.f,0.f};   // [n*4+q]
    float h_reg[8] = {0.f,0.f,0.f,0.f,0.f,0.f,0.f,0.f};

    for (int t = 0; t <= T_STEPS; ++t) {
        const int nb_t   = (t < T_STEPS) ? (int)nbL[t] : 0;
        const int nb_pre = (t > 0) ? (int)nbL[t - 1] : B_SZ;
        const __bf16* hin  = hbuf + (size_t)((t + RING - 1) & (RING - 1)) * HBUF_ELEMS;
        __bf16*       hout = hbuf + (size_t)(t & (RING - 1)) * HBUF_ELEMS;

        const bool gcomp = isGate && (t < T_STEPS) && (bti * 32 < nb_t);
        const bool gwrt  = isGate && (t < T_STEPS) && (bti * 32 < nb_pre);

        f32x16 acc[2];

        // ---- pre-barrier: bias + x_t @ W_ih^T (independent of h(t-1)) ----
        if (gcomp) {
            #pragma unroll
            for (int n = 0; n < 2; ++n) {
                float bv = biasL[n * 32 + col];
                #pragma unroll
                for (int i = 0; i < 16; ++i) acc[n][i] = bv;
            }
            const float* xrow = X + ((size_t)t * B_SZ + (bti * 32 + col)) * F_SZ;
            #pragma unroll
            for (int kt = 0; kt < 6; ++kt) {
                int f0 = kt * 16 + h5 * 8;
                bf16x8 a;
                if (f0 < F_SZ) {
                    float4 lo = *(const float4*)(xrow + f0);
                    float4 hi = *(const float4*)(xrow + f0 + 4);
                    a[0] = (__bf16)lo.x; a[1] = (__bf16)lo.y; a[2] = (__bf16)lo.z; a[3] = (__bf16)lo.w;
                    a[4] = (__bf16)hi.x; a[5] = (__bf16)hi.y; a[6] = (__bf16)hi.z; a[7] = (__bf16)hi.w;
                } else {
                    #pragma unroll
                    for (int j = 0; j < 8; ++j) a[j] = (__bf16)0.0f;
                }
                #pragma unroll
                for (int n = 0; n < 2; ++n)
                    acc[n] = __builtin_amdgcn_mfma_f32_32x32x16_bf16(a, wih[n][kt], acc[n], 0, 0, 0);
            }
        }

        // ---- per-wave group barrier: poll this group's 64 gate + 3 FC lines ----
        {
            const int target = t + 1;
            for (;;) {
                int a = __hip_atomic_load(flags + (gbase + lane) * FLAG_STRIDE,
                                          __ATOMIC_RELAXED, __HIP_MEMORY_SCOPE_AGENT);
                int b = (lane < 3) ? __hip_atomic_load(flags + (gbase + 64 + lane) * FLAG_STRIDE,
                                                       __ATOMIC_RELAXED, __HIP_MEMORY_SCOPE_AGENT)
                                   : target;
                if (__all((a >= target) && (b >= target))) break;
                __builtin_amdgcn_s_sleep(1);
                if (++guard > 400000000L) break;     // anti-hang bail
            }
            // compiler fence: h loads below cannot hoist above the poll (R1 bug)
            asm volatile("" ::: "memory");
        }

        // ---- staggered periodic acquire (buffer_inv), once per ring window ----
        if (((t + phase) & (RING - 1)) == 0)
            __builtin_amdgcn_fence(__ATOMIC_ACQUIRE, "agent");

        // FC waves arrive early (slack via the deep ring)
        if (!isGate && lane == 0) {
            __hip_atomic_store(flags + fidx * FLAG_STRIDE, t + 2, __ATOMIC_RELAXED,
                               __HIP_MEMORY_SCOPE_AGENT);
        }

        // ---- FC head: logits(t-1) from h(t-1) of this wave's tile ----
        if (!isGate && t >= 1) {
            const int  s        = t - 1;
            const int  nb_s     = (int)nbL[s];
            const bool act_tile = (bti * 32) < nb_s;
            f32x16 accf;
            #pragma unroll
            for (int i = 0; i < 16; ++i) accf[i] = 0.0f;
            if (act_tile) {
                float bv = biasL[col];
                #pragma unroll
                for (int i = 0; i < 16; ++i) accf[i] = bv;
                const __bf16* hA = hin + (size_t)bti * 512 + (size_t)lane * 8;
                const __bf16* bB = slab + lane * 8;
                #pragma unroll 8
                for (int kt = 0; kt < 64; ++kt) {
                    bf16x8 a = __builtin_bit_cast(bf16x8, *(const i32x4*)(hA + (size_t)kt * 2048));
                    bf16x8 b = __builtin_bit_cast(bf16x8, *(const i32x4*)(bB + (size_t)kt * 512));
                    accf = __builtin_amdgcn_mfma_f32_32x32x16_bf16(a, b, accf, 0, 0, 0);
                }
            }
            const int c = c0fc + col;
            if (c < C_SZ) {
                #pragma unroll
                for (int i = 0; i < 16; ++i) {
                    int row = (i & 3) + 8 * (i >> 2) + 4 * h5;
                    int b   = bti * 32 + row;
                    float v = (act_tile && b < nb_s) ? accf[i] : 0.0f;
                    float2 o2; o2.x = v; o2.y = 1.0f - v;
                    *(float2*)(out + ((size_t)(b * T_STEPS + s) * C_SZ + c) * 2) = o2;
                }
            }
        }

        // ---- gate phase 1: h(t-1) @ W_hh^T, 2-ahead double-buffer pipeline ----
        if (gcomp && t > 0) {
            const __bf16* hA = hin + (size_t)bti * 512 + (size_t)lane * 8;
            const __bf16* bB = slab + lane * 8;
            i32x4 pf0[16], pf1[16];
            #pragma unroll
            for (int i = 0; i < 16; ++i)
                pf0[i] = *(const i32x4*)(hA + (size_t)i * 2048);
            #pragma unroll
            for (int i = 0; i < 16; ++i)
                pf1[i] = *(const i32x4*)(hA + (size_t)(16 + i) * 2048);
            __builtin_amdgcn_sched_barrier(0);   // keep the 32-load burst clustered
            #pragma unroll
            for (int c = 0; c < 4; ++c) {
                i32x4 (&cur)[16] = (c & 1) ? pf1 : pf0;
                #pragma unroll
                for (int i = 0; i < 16; ++i) {
                    bf16x8 a = __builtin_bit_cast(bf16x8, cur[i]);
                    const int ks = c * 16 + i;
                    bf16x8 b0 = __builtin_bit_cast(bf16x8,
                        *(const i32x4*)(bB + (size_t)ks * 1024));
                    acc[0] = __builtin_amdgcn_mfma_f32_32x32x16_bf16(a, b0, acc[0], 0, 0, 0);
                    bf16x8 b1 = __builtin_bit_cast(bf16x8,
                        *(const i32x4*)(bB + (size_t)ks * 1024 + 512));
                    acc[1] = __builtin_amdgcn_mfma_f32_32x32x16_bf16(a, b1, acc[1], 0, 0, 0);
                    if (c < 2)   // refill this slot with chunk c+2's element i
                        cur[i] = *(const i32x4*)(hA + (size_t)((c + 2) * 16 + i) * 2048);
                }
                __builtin_amdgcn_sched_barrier(0);
            }
        }

        // ---- gate phase 2: exch (same-wave LDS), activations, state update ----
        if (gcomp) {
            #pragma unroll
            for (int n = 0; n < 2; ++n)
                #pragma unroll
                for (int j = 0; j < 16; ++j)
                    exch[(n * 16 + j) * 68 + lane] = acc[n][j];
            // same-wave LDS RAW: drain ds_writes before transposed reads
            asm volatile("s_waitcnt lgkmcnt(0)" ::: "memory");
            __builtin_amdgcn_sched_barrier(0);
            #pragma unroll
            for (int n = 0; n < 2; ++n) {
                #pragma unroll
                for (int q = 0; q < 4; ++q) {
                    const float4 v = *(const float4*)(exch + (n * 16 + 4 * a4 + q) * 68 + 32 * h5 + (col & ~3));
                    float si = sigm(v.x);
                    float sf = sigm(v.y);
                    float tg = tanh_fast(v.z);
                    float so = sigm(v.w);
                    float cn = sf * c_reg[n * 4 + q] + si * tg;
                    float hn = so * tanh_fast(cn);
                    int b = bti * 32 + 8 * a4 + 4 * h5 + q;
                    if (b < nb_t) { c_reg[n * 4 + q] = cn; h_reg[n * 4 + q] = hn; }
                }
            }
        }

        // ---- gate phase 3: stage (same-wave LDS) + write-through store ----
        if (gwrt) {
            #pragma unroll
            for (int n = 0; n < 2; ++n)
                #pragma unroll
                for (int q = 0; q < 4; ++q)
                    stageW[(8 * a4 + 4 * h5 + q) * 16 + n * 8 + u0] = (__bf16)h_reg[n * 4 + q];
            asm volatile("s_waitcnt lgkmcnt(0)" ::: "memory");
            __builtin_amdgcn_sched_barrier(0);
            const uint64_t* sp = (const uint64_t*)(stageW + (size_t)col * 16 + (size_t)h5 * 8);
            uint64_t* hp = (uint64_t*)(hout + (size_t)ug * 2048 + (size_t)bti * 512 + (size_t)lane * 8);
            st_llc(hp,     sp[0]);
            st_llc(hp + 1, sp[1]);
        }

        // ---- per-wave arrival: drain own stores, signal own flag ----
        if (isGate) {
            asm volatile("" ::: "memory");
            __builtin_amdgcn_s_waitcnt(0);       // st_llc of h(t) at the LLC
            if (lane == 0)
                __hip_atomic_store(flags + fidx * FLAG_STRIDE, t + 2, __ATOMIC_RELAXED,
                                   __HIP_MEMORY_SCOPE_AGENT);
        }
    }
}

extern "C" void kernel_launch(void* const* d_in, const int* in_sizes, int n_in,
                              void* d_out, int out_size, void* d_ws, size_t ws_size,
                              hipStream_t stream) {
    const float* X    = (const float*)d_in[0];
    const int*   lens = (const int*)d_in[1];
    const float* Wih  = (const float*)d_in[2];
    const float* Whh  = (const float*)d_in[3];
    const float* bih  = (const float*)d_in[4];
    const float* bhh  = (const float*)d_in[5];
    const float* Wfc  = (const float*)d_in[6];
    const float* bfc  = (const float*)d_in[7];
    float*       outp = (float*)d_out;

    __bf16* hbuf  = (__bf16*)d_ws;                                 // RING x 256 KB
    int*    flags = (int*)((char*)d_ws + (size_t)RING * HBUF_BYTES); // 272 lines

    (void)hipFuncSetAttribute((const void*)lstm_fused,
                              hipFuncAttributeMaxDynamicSharedMemorySize, SMEM_BYTES);

    void* args[] = { (void*)&X, (void*)&lens, (void*)&Wih, (void*)&Whh,
                     (void*)&bih, (void*)&bhh, (void*)&Wfc, (void*)&bfc,
                     (void*)&outp, (void*)&hbuf, (void*)&flags };
    hipError_t le = hipLaunchCooperativeKernel((void*)lstm_fused, dim3(N_WG), dim3(BLOCK),
                                               args, (unsigned)SMEM_BYTES, stream);
    if (le != hipSuccess) {
        // fallback: plain launch. 134 WGs, 1 per CU (LDS-limited) on 256 CUs are
        // co-resident; the kernel uses only its own flag barrier, no cg grid sync.
        hipLaunchKernelGGL(lstm_fused, dim3(N_WG), dim3(BLOCK),
                           (unsigned)SMEM_BYTES, stream,
                           X, lens, Wih, Whh, bih, bhh, Wfc, bfc, outp, hbuf, flags);
    }
}